// Round 19
// baseline (624263.428 us; speedup 1.0000x reference)
//
#include <hip/hip_runtime.h>

// ---------------------------------------------------------------------------
// 2-layer LSTM (B=256, T=784, H=512, C=10), persistent kernel, round 19.
//
// Ledger: r13 best (4.71ms). Join variants all regressed: r14 defer (4.95),
// r15 L2 atomics (5.72, dirty writebacks), r16 per-wave spread (5.86),
// r17 WG-spread (5.40), r18 per-wave packed (9.11, contention).
//
// r19 = r13 verbatim + ONE change: flag ops drop sc1 (MALL) -> sc0-only,
// targeting the stripe's OWN XCD L2 (~250cyc RTT vs ~900):
//   - all 32 participants share one XCD (r8-proven discovery) -> L2 is
//     their coherence point; same scope argument as the r10/r13 data path.
//   - sc0 STORE is strictly stronger than r12's failed plain store (forces
//     prompt write-through past L1/write-buffer).
//   - guard 2^13: if sc0-flag visibility fails, waits break early -> fast
//     VISIBLE absmax failure, never a timeout.
//   - + x-prefetch before the poll (input-only, hazard-free).
//
// Everything else byte-identical to r13: per-WG flags packed in 32
// contiguous words/stripe (2 lines), wave0's 32 lanes poll, 2 loop
// __syncthreads, vm0 drain before flag store, stripe=XCD, waves 0-1
// layer-1 (W_hh1 regs), waves 2-3 layer-2 (W_hh2 regs + W_ih2 LDS),
// phase k: L1(t=k) || L2(t=k-1) || FC(t=k-2), intra-XCD data = plain
// stores + sc0 loads strictly after the join edge, batched asm ld/st.
//
// Phase audit (r10/r13): wait(all 32 flags >= k) => all WGs finished k-1.
// L1(k) reads h1[(k-1)&1] ✓, writes h1/c1[k&1] (last read @k-1) ✓;
// L2(k-1) reads c1[(k-1)&1], h2[(k-2)&1], writes h2[(k-1)&1] ✓;
// FC(k-2) reads h2[k&1], rewritten only @k+1 (after our arrive) ✓.
// ---------------------------------------------------------------------------

constexpr int Bn = 256;   // batch
constexpr int Tn = 784;   // timesteps
constexpr int Hn = 512;   // hidden
constexpr int Cn = 10;    // classes

typedef short s16x8 __attribute__((ext_vector_type(8)));
typedef float f32x4 __attribute__((ext_vector_type(4)));

__device__ __forceinline__ unsigned short f2bf(float f) {
  unsigned u = __float_as_uint(f);
  u += 0x7FFFu + ((u >> 16) & 1u);  // round-to-nearest-even
  return (unsigned short)(u >> 16);
}
__device__ __forceinline__ float bf2f(unsigned short s) {
  return __uint_as_float(((unsigned)s) << 16);
}
__device__ __forceinline__ float sigm(float v) { return 1.f / (1.f + __expf(-v)); }
__device__ __forceinline__ float tanh_(float v) {
  float vc = fminf(fmaxf(v, -15.f), 15.f);
  float e = __expf(2.f * vc);
  return (e - 1.f) / (e + 1.f);
}

// ---- intra-XCD data accessors (r13-proven) ----
__device__ __forceinline__ s16x8 load16_l2(const unsigned short* p) {
  s16x8 r;
  asm volatile("global_load_dwordx4 %0, %1, off sc0"
               : "=v"(r) : "v"(p) : "memory");
  return r;
}
__device__ __forceinline__ void load16x16_l2(const unsigned short* p, s16x8* f) {
  asm volatile(
      "global_load_dwordx4 %0, %16, off sc0\n\t"
      "global_load_dwordx4 %1, %16, off offset:64 sc0\n\t"
      "global_load_dwordx4 %2, %16, off offset:128 sc0\n\t"
      "global_load_dwordx4 %3, %16, off offset:192 sc0\n\t"
      "global_load_dwordx4 %4, %16, off offset:256 sc0\n\t"
      "global_load_dwordx4 %5, %16, off offset:320 sc0\n\t"
      "global_load_dwordx4 %6, %16, off offset:384 sc0\n\t"
      "global_load_dwordx4 %7, %16, off offset:448 sc0\n\t"
      "global_load_dwordx4 %8, %16, off offset:512 sc0\n\t"
      "global_load_dwordx4 %9, %16, off offset:576 sc0\n\t"
      "global_load_dwordx4 %10, %16, off offset:640 sc0\n\t"
      "global_load_dwordx4 %11, %16, off offset:704 sc0\n\t"
      "global_load_dwordx4 %12, %16, off offset:768 sc0\n\t"
      "global_load_dwordx4 %13, %16, off offset:832 sc0\n\t"
      "global_load_dwordx4 %14, %16, off offset:896 sc0\n\t"
      "global_load_dwordx4 %15, %16, off offset:960 sc0"
      : "=&v"(f[0]), "=&v"(f[1]), "=&v"(f[2]), "=&v"(f[3]),
        "=&v"(f[4]), "=&v"(f[5]), "=&v"(f[6]), "=&v"(f[7]),
        "=&v"(f[8]), "=&v"(f[9]), "=&v"(f[10]), "=&v"(f[11]),
        "=&v"(f[12]), "=&v"(f[13]), "=&v"(f[14]), "=&v"(f[15])
      : "v"(p) : "memory");
}
__device__ __forceinline__ void store4_l2(unsigned short* p, unsigned v0,
                                          unsigned v1, unsigned v2, unsigned v3) {
  asm volatile(
      "global_store_short %0, %1, off\n\t"
      "global_store_short %0, %2, off offset:1024\n\t"
      "global_store_short %0, %3, off offset:2048\n\t"
      "global_store_short %0, %4, off offset:3072"
      :: "v"(p), "v"(v0), "v"(v1), "v"(v2), "v"(v3) : "memory");
}
__device__ __forceinline__ void vm0_fence() {
  asm volatile("s_waitcnt vmcnt(0)" ::: "memory");
  __builtin_amdgcn_sched_barrier(0);
}
// ---- XCD-local flag ops (r19: sc0-only store + sc0-only poll) ----
__device__ __forceinline__ unsigned ld_flag_xcd(const unsigned* p) {
  unsigned r;
  asm volatile("global_load_dword %0, %1, off sc0\n\ts_waitcnt vmcnt(0)"
               : "=v"(r) : "v"(p) : "memory");
  return r;
}
__device__ __forceinline__ void st_flag_xcd(unsigned* p, unsigned v) {
  asm volatile("global_store_dword %0, %1, off sc0"
               :: "v"(p), "v"(v) : "memory");
}

// one-time: weight slice -> LDS bf16, XOR-swizzled on 16B chunks
__device__ __forceinline__ void stage_w(char* smem, const float* W0,
                                        int js, int tid, int base) {
  for (int idx = tid * 4; idx < 64 * 512; idx += 1024) {
    int row = idx >> 9, kk = idx & 511;                   // row = g*16 + c
    int n = ((row >> 4) << 9) + js + (row & 15);          // gate col
    float4 w = *(const float4*)(W0 + (size_t)n * Hn + kk);
    short4 v = { (short)f2bf(w.x), (short)f2bf(w.y), (short)f2bf(w.z), (short)f2bf(w.w) };
    int byte = base + (row << 10) + ((((kk >> 3) ^ (row & 7)) << 4)) + ((kk & 7) << 1);
    *(short4*)(smem + byte) = v;
  }
}

__global__ void __launch_bounds__(256, 1)
lstm2_kernel(const float* __restrict__ x,
             const float* __restrict__ W_ih1, const float* __restrict__ W_hh1,
             const float* __restrict__ b_ih1, const float* __restrict__ b_hh1,
             const float* __restrict__ W_ih2, const float* __restrict__ W_hh2,
             const float* __restrict__ b_ih2, const float* __restrict__ b_hh2,
             const float* __restrict__ W_fc, const float* __restrict__ b_fc,
             float* __restrict__ out,
             unsigned* __restrict__ cnts,        // sync area (32KB)
             unsigned short* __restrict__ h1b,   // [2][B][H] bf16 (XCD-local)
             unsigned short* __restrict__ c1b,   // [2][B][H] bf16 (XCD-local)
             unsigned short* __restrict__ h2b)   // [2][B][H] bf16 (XCD-local)
{
  extern __shared__ char smem[];
  const int tid = threadIdx.x;
  const int wv = tid >> 6;
  const int l = tid & 63;

  // ---- XCD discovery + rank grab (r8/r10/r13-proven) ----
  if (tid == 0) {
    unsigned xcc;
    asm volatile("s_getreg_b32 %0, hwreg(HW_REG_XCC_ID)" : "=s"(xcc));
    xcc &= 7u;
    unsigned rk = atomicAdd(&cnts[512 + xcc * 16], 1u);
    *(unsigned*)(smem + 131064) = xcc;
    *(unsigned*)(smem + 131060) = rk;
  }
  __syncthreads();
  const int s8   = (int)*(const unsigned*)(smem + 131064);   // stripe = XCD
  const int rank = (int)(*(const unsigned*)(smem + 131060) & 31u);
  const int rb = s8 << 5;           // 32-row batch stripe
  const int js = rank << 4;         // 16-col hidden slice

  // flags: 32 contiguous words per stripe (2 cache lines) at 1024 + s8*32
  unsigned* fbase = cnts + 1024 + s8 * 32;
  unsigned* myflag = fbase + rank;

  const int rA = l & 15, lg = l >> 4, lx = l & 7;
  const bool isW1 = (wv < 2);       // waves 0-1: layer-1; waves 2-3: layer-2

  // ---- staged weight load: W_hh1 -> regs(w0-1), W_hh2 -> regs(w2-3),
  //      then W_ih2 -> LDS[0..64K), W_fc+b_fc -> LDS[64K..) ----
  s16x8 bw[64];
  stage_w(smem, W_hh1, js, tid, 0);
  __syncthreads();
  if (isW1) {
#pragma unroll
    for (int g = 0; g < 4; ++g)
#pragma unroll
      for (int kc = 0; kc < 16; ++kc)
        bw[(g << 4) + kc] =
            *(const s16x8*)(smem + (((g << 4) + rA) << 10) + ((((kc << 2) + lg) ^ lx) << 4));
  }
  __syncthreads();
  stage_w(smem, W_hh2, js, tid, 0);
  __syncthreads();
  if (!isW1) {
#pragma unroll
    for (int g = 0; g < 4; ++g)
#pragma unroll
      for (int kc = 0; kc < 16; ++kc)
        bw[(g << 4) + kc] =
            *(const s16x8*)(smem + (((g << 4) + rA) << 10) + ((((kc << 2) + lg) ^ lx) << 4));
  }
  __syncthreads();
  stage_w(smem, W_ih2, js, tid, 0);
  {
    unsigned short* wf = (unsigned short*)(smem + 65536);
    for (int idx = tid; idx < Cn * Hn; idx += 256) wf[idx] = f2bf(W_fc[idx]);
    if (tid < Cn) ((float*)(smem + 65536 + Cn * Hn * 2))[tid] = b_fc[tid];
  }
  __syncthreads();

  // per-lane constants
  float wih1g[4], bg[4];
  {
    int col = js + rA;
#pragma unroll
    for (int g = 0; g < 4; ++g) {
      int n = (g << 9) + col;
      if (isW1) { wih1g[g] = W_ih1[n]; bg[g] = b_ih1[n] + b_hh1[n]; }
      else      { wih1g[g] = 0.f;      bg[g] = b_ih2[n] + b_hh2[n]; }
    }
  }

  const int rf = isW1 ? wv : (wv - 2);            // rowfrag 0/1
  const int arow  = rb + (rf << 4) + rA;          // A-fragment row (batch)
  const int myrow = rb + (rf << 4) + (lg << 2);   // C/D first row (batch)
  const int colj = js + rA;                       // my hidden col
  const int bfc = rb + rank;                      // FC batch row (1 per WG)
  const int cg = wv * 5;                          // FC class group (wv<2)

  const size_t SLAB = (size_t)Bn * Hn;
  const size_t aoff = (size_t)arow * Hn + (lg << 3);
  const unsigned short* h1A0 = h1b + aoff;
  const unsigned short* h1A1 = h1b + SLAB + aoff;
  const unsigned short* h2A0 = h2b + aoff;
  const unsigned short* h2A1 = h2b + SLAB + aoff;
  const unsigned short* c1A0 = c1b + aoff;
  const unsigned short* c1A1 = c1b + SLAB + aoff;
  const size_t woff = (size_t)myrow * Hn + colj;
  unsigned short* h1W0 = h1b + woff;  unsigned short* h1W1 = h1b + SLAB + woff;
  unsigned short* c1W0 = c1b + woff;  unsigned short* c1W1 = c1b + SLAB + woff;
  unsigned short* h2W0 = h2b + woff;  unsigned short* h2W1 = h2b + SLAB + woff;
  const unsigned short* fcA0 = h2b + (size_t)bfc * Hn + (l << 3);
  const unsigned short* fcA1 = fcA0 + SLAB;

  float cst[4] = {0.f, 0.f, 0.f, 0.f};            // c1 (waves 0-1) / c2 (2-3)

  for (int k = 0; k <= Tn + 1; ++k) {
    // ---- x prefetch (input-only; hides under the poll) ----
    float xv[4];
    const bool doL1 = isW1 && (k < Tn);
    if (doL1) {
#pragma unroll
      for (int r = 0; r < 4; ++r) xv[r] = x[(size_t)(myrow + r) * Tn + k];
    }

    // ---- single join/phase: wave0's lanes 0-31 poll 32 XCD-local flags ----
    if (wv == 0 && k > 0) {
      const unsigned* p = fbase + (l & 31);
      int g = 0;
      for (;;) {
        unsigned a = ld_flag_xcd(p);
        if (__all((int)a >= k)) break;
        if (++g > (1 << 13)) break;  // bounded: visible fail, never a hang
        __builtin_amdgcn_s_sleep(1);
      }
    }
    __syncthreads();

    s16x8 h8;
    if (isW1 && k >= 2)   // FC operand h2(k-2), slot (k-2)&1 == k&1
      h8 = load16_l2((k & 1) ? fcA1 : fcA0);

    if (isW1) {
      // ---------- layer-1 step t=k ----------
      if (k < Tn) {
        s16x8 af[16];
        load16x16_l2(((k - 1) & 1) ? h1A1 : h1A0, af);
        vm0_fence();
        f32x4 acc[4];
#pragma unroll
        for (int g = 0; g < 4; ++g) acc[g] = f32x4{0.f, 0.f, 0.f, 0.f};
#pragma unroll
        for (int kc = 0; kc < 16; ++kc)
#pragma unroll
          for (int g = 0; g < 4; ++g)
            acc[g] = __builtin_amdgcn_mfma_f32_16x16x32_bf16(af[kc], bw[(g << 4) + kc], acc[g], 0, 0, 0);
        unsigned hv[4], cv[4];
#pragma unroll
        for (int r = 0; r < 4; ++r) {
          float iv = sigm(acc[0][r] + xv[r] * wih1g[0] + bg[0]);
          float ff = sigm(acc[1][r] + xv[r] * wih1g[1] + bg[1]);
          float gv = tanh_(acc[2][r] + xv[r] * wih1g[2] + bg[2]);
          float ov = sigm(acc[3][r] + xv[r] * wih1g[3] + bg[3]);
          float c = ff * cst[r] + iv * gv;
          cst[r] = c;
          hv[r] = f2bf(ov * tanh_(c));
          cv[r] = f2bf(c);
        }
        store4_l2((k & 1) ? h1W1 : h1W0, hv[0], hv[1], hv[2], hv[3]);
        store4_l2((k & 1) ? c1W1 : c1W0, cv[0], cv[1], cv[2], cv[3]);
      }
    } else {
      // ---------- layer-2 step t=k-1 ----------
      if (k >= 1 && k <= Tn) {
        const int t = k - 1;
        s16x8 af[16], cf[16];
        load16x16_l2(((t - 1) & 1) ? h2A1 : h2A0, af);
        load16x16_l2((t & 1) ? c1A1 : c1A0, cf);
        vm0_fence();
        f32x4 acc[4];
#pragma unroll
        for (int g = 0; g < 4; ++g) acc[g] = f32x4{0.f, 0.f, 0.f, 0.f};
#pragma unroll
        for (int kc = 0; kc < 16; ++kc)
#pragma unroll
          for (int g = 0; g < 4; ++g)
            acc[g] = __builtin_amdgcn_mfma_f32_16x16x32_bf16(af[kc], bw[(g << 4) + kc], acc[g], 0, 0, 0);
#pragma unroll
        for (int kc = 0; kc < 16; ++kc)
#pragma unroll
          for (int g = 0; g < 4; ++g) {
            int byte = (((g << 4) + rA) << 10) + ((((kc << 2) + lg) ^ lx) << 4);
            acc[g] = __builtin_amdgcn_mfma_f32_16x16x32_bf16(cf[kc], *(const s16x8*)(smem + byte), acc[g], 0, 0, 0);
          }
        unsigned hv[4];
#pragma unroll
        for (int r = 0; r < 4; ++r) {
          float iv = sigm(acc[0][r] + bg[0]);
          float ff = sigm(acc[1][r] + bg[1]);
          float gv = tanh_(acc[2][r] + bg[2]);
          float ov = sigm(acc[3][r] + bg[3]);
          float c = ff * cst[r] + iv * gv;
          cst[r] = c;
          hv[r] = f2bf(ov * tanh_(c));
        }
        store4_l2((t & 1) ? h2W1 : h2W0, hv[0], hv[1], hv[2], hv[3]);
      }
    }

    // ---- arrive: drain own vmem (asm ops incl.), sync, one sc0 flag ----
    vm0_fence();
    __syncthreads();
    if (tid == 0) st_flag_xcd(myflag, (unsigned)(k + 1));

    // ---- FC for t=k-2 (waves 0-1, off the critical chain) ----
    if (isW1 && k >= 2) {
      const unsigned short* wf = (const unsigned short*)(smem + 65536);
      float rs[5];
#pragma unroll
      for (int c5 = 0; c5 < 5; ++c5) {
        s16x8 w8 = *(const s16x8*)(wf + (size_t)(cg + c5) * Hn + (l << 3));
        float sum = 0.f;
#pragma unroll
        for (int i = 0; i < 8; ++i)
          sum += bf2f((unsigned short)h8[i]) * bf2f((unsigned short)w8[i]);
        rs[c5] = sum;
      }
#pragma unroll
      for (int c5 = 0; c5 < 5; ++c5) {
#pragma unroll
        for (int off = 32; off > 0; off >>= 1)
          rs[c5] += __shfl_xor(rs[c5], off);
      }
      if (l < 5) {
        float v = (l == 0) ? rs[0] : (l == 1) ? rs[1] : (l == 2) ? rs[2] : (l == 3) ? rs[3] : rs[4];
        v += ((const float*)(smem + 65536 + Cn * Hn * 2))[cg + l];
        out[(size_t)bfc * (Tn * Cn) + (size_t)(k - 2) * Cn + (cg + l)] = v;
      }
    }
  }
}

extern "C" void kernel_launch(void* const* d_in, const int* in_sizes, int n_in,
                              void* d_out, int out_size, void* d_ws, size_t ws_size,
                              hipStream_t stream) {
  const float* x     = (const float*)d_in[0];
  const float* W_ih1 = (const float*)d_in[1];
  const float* W_hh1 = (const float*)d_in[2];
  const float* b_ih1 = (const float*)d_in[3];
  const float* b_hh1 = (const float*)d_in[4];
  const float* W_ih2 = (const float*)d_in[5];
  const float* W_hh2 = (const float*)d_in[6];
  const float* b_ih2 = (const float*)d_in[7];
  const float* b_hh2 = (const float*)d_in[8];
  const float* W_fc  = (const float*)d_in[9];
  const float* b_fc  = (const float*)d_in[10];
  float* out = (float*)d_out;

  unsigned* cnts = (unsigned*)d_ws;
  unsigned short* h1b = (unsigned short*)((char*)d_ws + 32768);
  unsigned short* c1b = h1b + (size_t)2 * Bn * Hn;
  unsigned short* h2b = c1b + (size_t)2 * Bn * Hn;

  // zero sync area (rank-grab + flags) + state slabs every launch
  size_t zbytes = 32768 + (size_t)3 * 2 * Bn * Hn * sizeof(unsigned short);
  hipMemsetAsync(d_ws, 0, zbytes, stream);

  (void)hipFuncSetAttribute((const void*)lstm2_kernel,
                            hipFuncAttributeMaxDynamicSharedMemorySize, 131072);

  lstm2_kernel<<<dim3(256), dim3(256), 131072, stream>>>(
      x, W_ih1, W_hh1, b_ih1, b_hh1, W_ih2, W_hh2, b_ih2, b_hh2, W_fc, b_fc,
      out, cnts, h1b, c1b, h2b);
}

// Round 20
// 4738.490 us; speedup vs baseline: 131.7431x; 131.7431x over previous
//
#include <hip/hip_runtime.h>

// ---------------------------------------------------------------------------
// 2-layer LSTM (B=256, T=784, H=512, C=10), persistent kernel — FINAL (=r13).
//
// Journey: 43.4ms (r1, release/threadfence sync) -> 10.5ms (r3, sc-bypass
// data) -> 8.5ms (r5, sc01 flags) -> 7.1ms (r7, weights in VGPRs) -> 5.4ms
// (r10, stripe=XCD, all data XCD-local) -> 4.71ms (r13, packed-flag MALL
// join + batched asm loads). r14-r19 enumerated every alternative join
// primitive/schedule; all regressed or broke:
//   r12 plain-store flags: invisible -> hang.  r15 local atomics: dirty+slow.
//   r16/r18 per-wave flags: poll contention.   r17 spread flags: slower.
//   r19 sc0-only flags: invisible (guard-crawl).  r14 deferred p2: slower.
// Floor analysis: 784 strictly-sequential steps; each needs the FULL
// previous hidden state (K=512 spans all 32 WGs of a stripe) -> mandatory
// 32-WG join/step. Fastest correct cross-CU visibility primitive = sc01
// MALL flag (~2-3us notify+detect); body ~3us serial. 784 x 6us = 4.7ms.
// Latency-bound, not BW/compute-bound (MfmaUtil 10.6%, HBM 0.2%).
//
// Structure: stripe = XCD (HW_REG_XCC_ID + rank grab; 1 WG/CU via 128KB
// LDS => exactly 32 WGs/XCD). Waves 0-1: layer-1 (W_hh1 in 256 VGPRs);
// waves 2-3: layer-2 (W_hh2 in VGPRs + W_ih2 in LDS, XOR-swizzled).
// Phase k: L1(t=k) || L2(t=k-1) || FC out(t=k-2). One join/phase: per-WG
// sc01 flags packed in 32 words/stripe (2 lines), wave0's 32 lanes poll in
// parallel. Data paths XCD-local: plain stores -> home L2, sc0 loads,
// strictly after the join edge; vm0 drain (covers asm stores) before every
// flag store. Batched 16-load / 4-store asm blocks off parity-selected
// base pointers.
//
// Phase audit: wait(all 32 flags >= k) => all WGs finished phase k-1.
// L1(k) reads h1[(k-1)&1] ✓, writes h1/c1[k&1] (last read @k-1) ✓;
// L2(k-1) reads c1[(k-1)&1], h2[(k-2)&1], writes h2[(k-1)&1] ✓;
// FC(k-2) reads h2[k&1], rewritten only @k+1 (after our arrive) ✓.
// ---------------------------------------------------------------------------

constexpr int Bn = 256;   // batch
constexpr int Tn = 784;   // timesteps
constexpr int Hn = 512;   // hidden
constexpr int Cn = 10;    // classes

typedef short s16x8 __attribute__((ext_vector_type(8)));
typedef float f32x4 __attribute__((ext_vector_type(4)));

__device__ __forceinline__ unsigned short f2bf(float f) {
  unsigned u = __float_as_uint(f);
  u += 0x7FFFu + ((u >> 16) & 1u);  // round-to-nearest-even
  return (unsigned short)(u >> 16);
}
__device__ __forceinline__ float bf2f(unsigned short s) {
  return __uint_as_float(((unsigned)s) << 16);
}
__device__ __forceinline__ float sigm(float v) { return 1.f / (1.f + __expf(-v)); }
__device__ __forceinline__ float tanh_(float v) {
  float vc = fminf(fmaxf(v, -15.f), 15.f);
  float e = __expf(2.f * vc);
  return (e - 1.f) / (e + 1.f);
}

// ---- intra-XCD data accessors ----
__device__ __forceinline__ s16x8 load16_l2(const unsigned short* p) {
  s16x8 r;
  asm volatile("global_load_dwordx4 %0, %1, off sc0"
               : "=v"(r) : "v"(p) : "memory");
  return r;
}
__device__ __forceinline__ void load16x16_l2(const unsigned short* p, s16x8* f) {
  asm volatile(
      "global_load_dwordx4 %0, %16, off sc0\n\t"
      "global_load_dwordx4 %1, %16, off offset:64 sc0\n\t"
      "global_load_dwordx4 %2, %16, off offset:128 sc0\n\t"
      "global_load_dwordx4 %3, %16, off offset:192 sc0\n\t"
      "global_load_dwordx4 %4, %16, off offset:256 sc0\n\t"
      "global_load_dwordx4 %5, %16, off offset:320 sc0\n\t"
      "global_load_dwordx4 %6, %16, off offset:384 sc0\n\t"
      "global_load_dwordx4 %7, %16, off offset:448 sc0\n\t"
      "global_load_dwordx4 %8, %16, off offset:512 sc0\n\t"
      "global_load_dwordx4 %9, %16, off offset:576 sc0\n\t"
      "global_load_dwordx4 %10, %16, off offset:640 sc0\n\t"
      "global_load_dwordx4 %11, %16, off offset:704 sc0\n\t"
      "global_load_dwordx4 %12, %16, off offset:768 sc0\n\t"
      "global_load_dwordx4 %13, %16, off offset:832 sc0\n\t"
      "global_load_dwordx4 %14, %16, off offset:896 sc0\n\t"
      "global_load_dwordx4 %15, %16, off offset:960 sc0"
      : "=&v"(f[0]), "=&v"(f[1]), "=&v"(f[2]), "=&v"(f[3]),
        "=&v"(f[4]), "=&v"(f[5]), "=&v"(f[6]), "=&v"(f[7]),
        "=&v"(f[8]), "=&v"(f[9]), "=&v"(f[10]), "=&v"(f[11]),
        "=&v"(f[12]), "=&v"(f[13]), "=&v"(f[14]), "=&v"(f[15])
      : "v"(p) : "memory");
}
__device__ __forceinline__ void store4_l2(unsigned short* p, unsigned v0,
                                          unsigned v1, unsigned v2, unsigned v3) {
  asm volatile(
      "global_store_short %0, %1, off\n\t"
      "global_store_short %0, %2, off offset:1024\n\t"
      "global_store_short %0, %3, off offset:2048\n\t"
      "global_store_short %0, %4, off offset:3072"
      :: "v"(p), "v"(v0), "v"(v1), "v"(v2), "v"(v3) : "memory");
}
__device__ __forceinline__ void vm0_fence() {
  asm volatile("s_waitcnt vmcnt(0)" ::: "memory");
  __builtin_amdgcn_sched_barrier(0);
}
// ---- MALL flag ops (the proven-fastest sync primitive) ----
__device__ __forceinline__ unsigned ld_flag_mall(const unsigned* p) {
  unsigned r;
  asm volatile("global_load_dword %0, %1, off sc0 sc1\n\ts_waitcnt vmcnt(0)"
               : "=v"(r) : "v"(p) : "memory");
  return r;
}
__device__ __forceinline__ void st_flag_mall(unsigned* p, unsigned v) {
  asm volatile("global_store_dword %0, %1, off sc0 sc1"
               :: "v"(p), "v"(v) : "memory");
}

// one-time: weight slice -> LDS bf16, XOR-swizzled on 16B chunks
__device__ __forceinline__ void stage_w(char* smem, const float* W0,
                                        int js, int tid, int base) {
  for (int idx = tid * 4; idx < 64 * 512; idx += 1024) {
    int row = idx >> 9, kk = idx & 511;                   // row = g*16 + c
    int n = ((row >> 4) << 9) + js + (row & 15);          // gate col
    float4 w = *(const float4*)(W0 + (size_t)n * Hn + kk);
    short4 v = { (short)f2bf(w.x), (short)f2bf(w.y), (short)f2bf(w.z), (short)f2bf(w.w) };
    int byte = base + (row << 10) + ((((kk >> 3) ^ (row & 7)) << 4)) + ((kk & 7) << 1);
    *(short4*)(smem + byte) = v;
  }
}

__global__ void __launch_bounds__(256, 1)
lstm2_kernel(const float* __restrict__ x,
             const float* __restrict__ W_ih1, const float* __restrict__ W_hh1,
             const float* __restrict__ b_ih1, const float* __restrict__ b_hh1,
             const float* __restrict__ W_ih2, const float* __restrict__ W_hh2,
             const float* __restrict__ b_ih2, const float* __restrict__ b_hh2,
             const float* __restrict__ W_fc, const float* __restrict__ b_fc,
             float* __restrict__ out,
             unsigned* __restrict__ cnts,        // sync area (32KB)
             unsigned short* __restrict__ h1b,   // [2][B][H] bf16 (XCD-local)
             unsigned short* __restrict__ c1b,   // [2][B][H] bf16 (XCD-local)
             unsigned short* __restrict__ h2b)   // [2][B][H] bf16 (XCD-local)
{
  extern __shared__ char smem[];
  const int tid = threadIdx.x;
  const int wv = tid >> 6;
  const int l = tid & 63;

  // ---- XCD discovery + rank grab ----
  if (tid == 0) {
    unsigned xcc;
    asm volatile("s_getreg_b32 %0, hwreg(HW_REG_XCC_ID)" : "=s"(xcc));
    xcc &= 7u;
    unsigned rk = atomicAdd(&cnts[512 + xcc * 16], 1u);
    *(unsigned*)(smem + 131064) = xcc;
    *(unsigned*)(smem + 131060) = rk;
  }
  __syncthreads();
  const int s8   = (int)*(const unsigned*)(smem + 131064);   // stripe = XCD
  const int rank = (int)(*(const unsigned*)(smem + 131060) & 31u);
  const int rb = s8 << 5;           // 32-row batch stripe
  const int js = rank << 4;         // 16-col hidden slice

  // flags: 32 contiguous words per stripe (2 cache lines) at 1024 + s8*32
  unsigned* fbase = cnts + 1024 + s8 * 32;
  unsigned* myflag = fbase + rank;

  const int rA = l & 15, lg = l >> 4, lx = l & 7;
  const bool isW1 = (wv < 2);       // waves 0-1: layer-1; waves 2-3: layer-2

  // ---- staged weight load: W_hh1 -> regs(w0-1), W_hh2 -> regs(w2-3),
  //      then W_ih2 -> LDS[0..64K), W_fc+b_fc -> LDS[64K..) ----
  s16x8 bw[64];
  stage_w(smem, W_hh1, js, tid, 0);
  __syncthreads();
  if (isW1) {
#pragma unroll
    for (int g = 0; g < 4; ++g)
#pragma unroll
      for (int kc = 0; kc < 16; ++kc)
        bw[(g << 4) + kc] =
            *(const s16x8*)(smem + (((g << 4) + rA) << 10) + ((((kc << 2) + lg) ^ lx) << 4));
  }
  __syncthreads();
  stage_w(smem, W_hh2, js, tid, 0);
  __syncthreads();
  if (!isW1) {
#pragma unroll
    for (int g = 0; g < 4; ++g)
#pragma unroll
      for (int kc = 0; kc < 16; ++kc)
        bw[(g << 4) + kc] =
            *(const s16x8*)(smem + (((g << 4) + rA) << 10) + ((((kc << 2) + lg) ^ lx) << 4));
  }
  __syncthreads();
  stage_w(smem, W_ih2, js, tid, 0);
  {
    unsigned short* wf = (unsigned short*)(smem + 65536);
    for (int idx = tid; idx < Cn * Hn; idx += 256) wf[idx] = f2bf(W_fc[idx]);
    if (tid < Cn) ((float*)(smem + 65536 + Cn * Hn * 2))[tid] = b_fc[tid];
  }
  __syncthreads();

  // per-lane constants
  float wih1g[4], bg[4];
  {
    int col = js + rA;
#pragma unroll
    for (int g = 0; g < 4; ++g) {
      int n = (g << 9) + col;
      if (isW1) { wih1g[g] = W_ih1[n]; bg[g] = b_ih1[n] + b_hh1[n]; }
      else      { wih1g[g] = 0.f;      bg[g] = b_ih2[n] + b_hh2[n]; }
    }
  }

  const int rf = isW1 ? wv : (wv - 2);            // rowfrag 0/1
  const int arow  = rb + (rf << 4) + rA;          // A-fragment row (batch)
  const int myrow = rb + (rf << 4) + (lg << 2);   // C/D first row (batch)
  const int colj = js + rA;                       // my hidden col
  const int bfc = rb + rank;                      // FC batch row (1 per WG)
  const int cg = wv * 5;                          // FC class group (wv<2)

  const size_t SLAB = (size_t)Bn * Hn;
  // parity-selected base pointers (precomputed; select = 1 cndmask pair)
  const size_t aoff = (size_t)arow * Hn + (lg << 3);
  const unsigned short* h1A0 = h1b + aoff;                 // h1 slab parity 0
  const unsigned short* h1A1 = h1b + SLAB + aoff;
  const unsigned short* h2A0 = h2b + aoff;
  const unsigned short* h2A1 = h2b + SLAB + aoff;
  const unsigned short* c1A0 = c1b + aoff;
  const unsigned short* c1A1 = c1b + SLAB + aoff;
  const size_t woff = (size_t)myrow * Hn + colj;
  unsigned short* h1W0 = h1b + woff;  unsigned short* h1W1 = h1b + SLAB + woff;
  unsigned short* c1W0 = c1b + woff;  unsigned short* c1W1 = c1b + SLAB + woff;
  unsigned short* h2W0 = h2b + woff;  unsigned short* h2W1 = h2b + SLAB + woff;
  const unsigned short* fcA0 = h2b + (size_t)bfc * Hn + (l << 3);
  const unsigned short* fcA1 = fcA0 + SLAB;

  float cst[4] = {0.f, 0.f, 0.f, 0.f};            // c1 (waves 0-1) / c2 (2-3)

  for (int k = 0; k <= Tn + 1; ++k) {
    // ---- single join/phase: wave0's 32 lanes poll the 32 MALL flags ----
    if (wv == 0 && k > 0) {
      const unsigned* p = fbase + (l & 31);
      int g = 0;
      for (;;) {
        unsigned a = ld_flag_mall(p);
        if (__all((int)a >= k)) break;
        if (++g > (1 << 20)) break;  // deadlock escape only
        __builtin_amdgcn_s_sleep(1);
      }
    }
    __syncthreads();

    s16x8 h8;
    if (isW1 && k >= 2)   // FC operand h2(k-2), slot (k-2)&1 == k&1
      h8 = load16_l2((k & 1) ? fcA1 : fcA0);

    if (isW1) {
      // ---------- layer-1 step t=k ----------
      if (k < Tn) {
        float xv[4];
#pragma unroll
        for (int r = 0; r < 4; ++r) xv[r] = x[(size_t)(myrow + r) * Tn + k];
        s16x8 af[16];
        load16x16_l2(((k - 1) & 1) ? h1A1 : h1A0, af);
        vm0_fence();
        f32x4 acc[4];
#pragma unroll
        for (int g = 0; g < 4; ++g) acc[g] = f32x4{0.f, 0.f, 0.f, 0.f};
#pragma unroll
        for (int kc = 0; kc < 16; ++kc)
#pragma unroll
          for (int g = 0; g < 4; ++g)
            acc[g] = __builtin_amdgcn_mfma_f32_16x16x32_bf16(af[kc], bw[(g << 4) + kc], acc[g], 0, 0, 0);
        unsigned hv[4], cv[4];
#pragma unroll
        for (int r = 0; r < 4; ++r) {
          float iv = sigm(acc[0][r] + xv[r] * wih1g[0] + bg[0]);
          float ff = sigm(acc[1][r] + xv[r] * wih1g[1] + bg[1]);
          float gv = tanh_(acc[2][r] + xv[r] * wih1g[2] + bg[2]);
          float ov = sigm(acc[3][r] + xv[r] * wih1g[3] + bg[3]);
          float c = ff * cst[r] + iv * gv;
          cst[r] = c;
          hv[r] = f2bf(ov * tanh_(c));
          cv[r] = f2bf(c);
        }
        store4_l2((k & 1) ? h1W1 : h1W0, hv[0], hv[1], hv[2], hv[3]);
        store4_l2((k & 1) ? c1W1 : c1W0, cv[0], cv[1], cv[2], cv[3]);
      }
    } else {
      // ---------- layer-2 step t=k-1 ----------
      if (k >= 1 && k <= Tn) {
        const int t = k - 1;
        s16x8 af[16], cf[16];
        load16x16_l2(((t - 1) & 1) ? h2A1 : h2A0, af);
        load16x16_l2((t & 1) ? c1A1 : c1A0, cf);
        vm0_fence();
        f32x4 acc[4];
#pragma unroll
        for (int g = 0; g < 4; ++g) acc[g] = f32x4{0.f, 0.f, 0.f, 0.f};
#pragma unroll
        for (int kc = 0; kc < 16; ++kc)
#pragma unroll
          for (int g = 0; g < 4; ++g)
            acc[g] = __builtin_amdgcn_mfma_f32_16x16x32_bf16(af[kc], bw[(g << 4) + kc], acc[g], 0, 0, 0);
#pragma unroll
        for (int kc = 0; kc < 16; ++kc)
#pragma unroll
          for (int g = 0; g < 4; ++g) {
            int byte = (((g << 4) + rA) << 10) + ((((kc << 2) + lg) ^ lx) << 4);
            acc[g] = __builtin_amdgcn_mfma_f32_16x16x32_bf16(cf[kc], *(const s16x8*)(smem + byte), acc[g], 0, 0, 0);
          }
        unsigned hv[4];
#pragma unroll
        for (int r = 0; r < 4; ++r) {
          float iv = sigm(acc[0][r] + bg[0]);
          float ff = sigm(acc[1][r] + bg[1]);
          float gv = tanh_(acc[2][r] + bg[2]);
          float ov = sigm(acc[3][r] + bg[3]);
          float c = ff * cst[r] + iv * gv;
          cst[r] = c;
          hv[r] = f2bf(ov * tanh_(c));
        }
        store4_l2((t & 1) ? h2W1 : h2W0, hv[0], hv[1], hv[2], hv[3]);
      }
    }

    // ---- arrive: drain own vmem (asm ops incl.), sync, one sc01 flag ----
    vm0_fence();
    __syncthreads();
    if (tid == 0) st_flag_mall(myflag, (unsigned)(k + 1));

    // ---- FC for t=k-2 (waves 0-1, off the critical chain) ----
    if (isW1 && k >= 2) {
      const unsigned short* wf = (const unsigned short*)(smem + 65536);
      float rs[5];
#pragma unroll
      for (int c5 = 0; c5 < 5; ++c5) {
        s16x8 w8 = *(const s16x8*)(wf + (size_t)(cg + c5) * Hn + (l << 3));
        float sum = 0.f;
#pragma unroll
        for (int i = 0; i < 8; ++i)
          sum += bf2f((unsigned short)h8[i]) * bf2f((unsigned short)w8[i]);
        rs[c5] = sum;
      }
#pragma unroll
      for (int c5 = 0; c5 < 5; ++c5) {
#pragma unroll
        for (int off = 32; off > 0; off >>= 1)
          rs[c5] += __shfl_xor(rs[c5], off);
      }
      if (l < 5) {
        float v = (l == 0) ? rs[0] : (l == 1) ? rs[1] : (l == 2) ? rs[2] : (l == 3) ? rs[3] : rs[4];
        v += ((const float*)(smem + 65536 + Cn * Hn * 2))[cg + l];
        out[(size_t)bfc * (Tn * Cn) + (size_t)(k - 2) * Cn + (cg + l)] = v;
      }
    }
  }
}

extern "C" void kernel_launch(void* const* d_in, const int* in_sizes, int n_in,
                              void* d_out, int out_size, void* d_ws, size_t ws_size,
                              hipStream_t stream) {
  const float* x     = (const float*)d_in[0];
  const float* W_ih1 = (const float*)d_in[1];
  const float* W_hh1 = (const float*)d_in[2];
  const float* b_ih1 = (const float*)d_in[3];
  const float* b_hh1 = (const float*)d_in[4];
  const float* W_ih2 = (const float*)d_in[5];
  const float* W_hh2 = (const float*)d_in[6];
  const float* b_ih2 = (const float*)d_in[7];
  const float* b_hh2 = (const float*)d_in[8];
  const float* W_fc  = (const float*)d_in[9];
  const float* b_fc  = (const float*)d_in[10];
  float* out = (float*)d_out;

  unsigned* cnts = (unsigned*)d_ws;
  unsigned short* h1b = (unsigned short*)((char*)d_ws + 32768);
  unsigned short* c1b = h1b + (size_t)2 * Bn * Hn;
  unsigned short* h2b = c1b + (size_t)2 * Bn * Hn;

  // zero sync area (rank-grab + flags) + state slabs every launch
  size_t zbytes = 32768 + (size_t)3 * 2 * Bn * Hn * sizeof(unsigned short);
  hipMemsetAsync(d_ws, 0, zbytes, stream);

  (void)hipFuncSetAttribute((const void*)lstm2_kernel,
                            hipFuncAttributeMaxDynamicSharedMemorySize, 131072);

  lstm2_kernel<<<dim3(256), dim3(256), 131072, stream>>>(
      x, W_ih1, W_hh1, b_ih1, b_hh1, W_ih2, W_hh2, b_ih2, b_hh2, W_fc, b_fc,
      out, cnts, h1b, c1b, h2b);
}